// Round 2
// baseline (1465.088 us; speedup 1.0000x reference)
//
#include <hip/hip_runtime.h>
#include <math.h>

#define DIM 1024
#define HEADS 16
#define HDIM 64
#define SEQ 2048
#define BATCH 2

typedef __attribute__((ext_vector_type(8))) short short8;
typedef __attribute__((ext_vector_type(4))) float f32x4;

#define AS_K 40   // padded LDS k-stride (ushorts): breaks 64B-stride bank aliasing

// ---------------------------------------------------------------------------
// Split a f32 into hi/lo bf16 (round-to-nearest-even), bit-exact helpers.
// ---------------------------------------------------------------------------
__device__ __forceinline__ unsigned short bf16_rtn(float x) {
    union { float f; unsigned int u; } c; c.f = x;
    unsigned int r = c.u + 0x7fffu + ((c.u >> 16) & 1u);
    return (unsigned short)(r >> 16);
}
__device__ __forceinline__ void split_bf16(float x, unsigned short& hi, unsigned short& lo) {
    hi = bf16_rtn(x);
    union { unsigned int u; float f; } h; h.u = ((unsigned int)hi) << 16;
    lo = bf16_rtn(x - h.f);
}

// ---------------------------------------------------------------------------
// Weight prep: W [K][N] f32  ->  Wt_hi/Wt_lo [N][K] bf16 (transposed + split)
// 32x32 LDS tile transpose, 256 threads.
// ---------------------------------------------------------------------------
__global__ __launch_bounds__(256) void wt_split_kernel(
    const float* __restrict__ W, unsigned short* __restrict__ Wt_hi,
    unsigned short* __restrict__ Wt_lo, int K, int N)
{
    __shared__ float tile[32][33];
    const int k0 = blockIdx.y * 32, n0 = blockIdx.x * 32;
    const int r = threadIdx.x >> 5, c = threadIdx.x & 31;
#pragma unroll
    for (int i = 0; i < 4; ++i)
        tile[r + i * 8][c] = W[(size_t)(k0 + r + i * 8) * N + n0 + c];
    __syncthreads();
#pragma unroll
    for (int i = 0; i < 4; ++i) {
        const float v = tile[c][r + i * 8];
        unsigned short hi, lo;
        split_bf16(v, hi, lo);
        const size_t idx = (size_t)(n0 + r + i * 8) * K + k0 + c;
        Wt_hi[idx] = hi;
        Wt_lo[idx] = lo;
    }
}

// ---------------------------------------------------------------------------
// Split-bf16 MFMA GEMM: C[M][N] = A[M][K](f32) @ B[K][N] + bias
// B supplied pre-transposed+split: Bt_hi/Bt_lo [N][K] bf16.
// BM=BN=128, BK=32, 256 threads (4 waves, 2x2), 4x4 frags of 16x16x32 per wave.
// 3-term split accumulation: Ahi*Bhi + Ahi*Blo + Alo*Bhi.
// ---------------------------------------------------------------------------
__global__ __launch_bounds__(256) void gemm_split_kernel(
    const float* __restrict__ A,
    const unsigned short* __restrict__ Bt_hi,
    const unsigned short* __restrict__ Bt_lo,
    const float* __restrict__ bias,
    float* __restrict__ C, int M, int N, int K)
{
    __shared__ unsigned short As_hi[128 * AS_K];
    __shared__ unsigned short As_lo[128 * AS_K];
    __shared__ unsigned short Bs_hi[128 * AS_K];
    __shared__ unsigned short Bs_lo[128 * AS_K];

    const int tid = threadIdx.x;
    const int bm = blockIdx.y * 128, bn = blockIdx.x * 128;
    const int w = tid >> 6, lane = tid & 63;
    const int wm = (w >> 1) * 64, wn = (w & 1) * 64;
    const int fr = lane & 15;          // row (A) / col (B) within fragment
    const int ko = (lane >> 4) * 8;    // k offset within fragment

    // staging assignment: 2 threads per row, 16 elems each
    const int ar = tid >> 1, ac = (tid & 1) * 16;
    const float* ap = A + (size_t)(bm + ar) * K + ac;
    const unsigned short* bph = Bt_hi + (size_t)(bn + ar) * K + ac;
    const unsigned short* bpl = Bt_lo + (size_t)(bn + ar) * K + ac;

    f32x4 acc[4][4];
#pragma unroll
    for (int i = 0; i < 4; ++i)
#pragma unroll
        for (int j = 0; j < 4; ++j)
            acc[i][j] = (f32x4){0.f, 0.f, 0.f, 0.f};

    float4 av[4];
    float4 bh[2], bl[2];

    // issue loads for step 0
#pragma unroll
    for (int i = 0; i < 4; ++i) av[i] = ((const float4*)ap)[i];
    bh[0] = ((const float4*)bph)[0]; bh[1] = ((const float4*)bph)[1];
    bl[0] = ((const float4*)bpl)[0]; bl[1] = ((const float4*)bpl)[1];

    const int nsteps = K / 32;
    for (int s = 0; s < nsteps; ++s) {
        __syncthreads();   // previous compute done reading LDS
        // convert + store A
        {
            unsigned int hw[8], lw[8];
            const float* af = (const float*)av;
#pragma unroll
            for (int i = 0; i < 8; ++i) {
                unsigned short h0, l0, h1, l1;
                split_bf16(af[2 * i], h0, l0);
                split_bf16(af[2 * i + 1], h1, l1);
                hw[i] = (unsigned int)h0 | ((unsigned int)h1 << 16);
                lw[i] = (unsigned int)l0 | ((unsigned int)l1 << 16);
            }
            unsigned int* dh = (unsigned int*)&As_hi[ar * AS_K + ac];
            unsigned int* dl = (unsigned int*)&As_lo[ar * AS_K + ac];
            *(uint4*)(dh + 0) = *(uint4*)&hw[0];
            *(uint4*)(dh + 4) = *(uint4*)&hw[4];
            *(uint4*)(dl + 0) = *(uint4*)&lw[0];
            *(uint4*)(dl + 4) = *(uint4*)&lw[4];
        }
        // store B (already bf16)
        {
            unsigned int* dh = (unsigned int*)&Bs_hi[ar * AS_K + ac];
            unsigned int* dl = (unsigned int*)&Bs_lo[ar * AS_K + ac];
            *(uint4*)(dh + 0) = *(uint4*)&bh[0];
            *(uint4*)(dh + 4) = *(uint4*)&bh[1];
            *(uint4*)(dl + 0) = *(uint4*)&bl[0];
            *(uint4*)(dl + 4) = *(uint4*)&bl[1];
        }
        __syncthreads();

        // prefetch next step's globals (overlaps with MFMA below)
        if (s + 1 < nsteps) {
            const int k0 = (s + 1) * 32;
#pragma unroll
            for (int i = 0; i < 4; ++i) av[i] = ((const float4*)(ap + k0))[i];
            bh[0] = ((const float4*)(bph + k0))[0]; bh[1] = ((const float4*)(bph + k0))[1];
            bl[0] = ((const float4*)(bpl + k0))[0]; bl[1] = ((const float4*)(bpl + k0))[1];
        }

        // fragment loads
        short8 a_hi[4], a_lo[4], b_hi[4], b_lo[4];
#pragma unroll
        for (int f = 0; f < 4; ++f) {
            const int arow = (wm + f * 16 + fr) * AS_K + ko;
            a_hi[f] = *(const short8*)&As_hi[arow];
            a_lo[f] = *(const short8*)&As_lo[arow];
            const int brow = (wn + f * 16 + fr) * AS_K + ko;
            b_hi[f] = *(const short8*)&Bs_hi[brow];
            b_lo[f] = *(const short8*)&Bs_lo[brow];
        }
        // 48 MFMAs
#pragma unroll
        for (int fm = 0; fm < 4; ++fm)
#pragma unroll
            for (int fn = 0; fn < 4; ++fn) {
                f32x4 c = acc[fm][fn];
                c = __builtin_amdgcn_mfma_f32_16x16x32_bf16(a_hi[fm], b_hi[fn], c, 0, 0, 0);
                c = __builtin_amdgcn_mfma_f32_16x16x32_bf16(a_hi[fm], b_lo[fn], c, 0, 0, 0);
                c = __builtin_amdgcn_mfma_f32_16x16x32_bf16(a_lo[fm], b_hi[fn], c, 0, 0, 0);
                acc[fm][fn] = c;
            }
    }

    // epilogue: bias + store (C/D layout: col=lane&15, row=(lane>>4)*4+reg)
    float bv[4];
#pragma unroll
    for (int fn = 0; fn < 4; ++fn) bv[fn] = bias[bn + wn + fn * 16 + fr];
#pragma unroll
    for (int fm = 0; fm < 4; ++fm) {
        const int row0 = bm + wm + fm * 16 + (lane >> 4) * 4;
#pragma unroll
        for (int fn = 0; fn < 4; ++fn) {
            const int col = bn + wn + fn * 16 + fr;
#pragma unroll
            for (int r = 0; r < 4; ++r)
                C[(size_t)(row0 + r) * N + col] = acc[fm][fn][r] + bv[fn];
        }
    }
}

// ---------------------------------------------------------------------------
// Flash-style causal attention, fp32, 4 queries per thread.
// Block: 256 threads = 64 slots x 4 dim-parts; thread owns queries
// qb + slot + {0,64,128,192}; K/V chunks (64 keys) staged in LDS and each
// register load amortized over 4 queries.
// ---------------------------------------------------------------------------
__device__ __forceinline__ float dot4(float4 a, float4 b) {
    return a.x * b.x + a.y * b.y + a.z * b.z + a.w * b.w;
}

__global__ __launch_bounds__(256) void attn_kernel(
    const float* __restrict__ qkv, float* __restrict__ y)
{
    const int C3 = 3 * DIM;
    const int qb = (int)(gridDim.x - 1 - blockIdx.x) * 256;  // heavy blocks first
    const int h = blockIdx.y;
    const int b = blockIdx.z;
    const int tid = threadIdx.x;
    const int part = tid & 3;     // 16-dim slice
    const int slot = tid >> 2;    // 0..63

    const float* base = qkv + (size_t)b * SEQ * C3;

    __shared__ float4 Ks[64 * 16];
    __shared__ float4 Vs[64 * 16];

    int qi[4];
    float4 qv[4][4];
#pragma unroll
    for (int r = 0; r < 4; ++r) {
        qi[r] = qb + slot + r * 64;
        const float4* qp = (const float4*)(base + (size_t)qi[r] * C3 + h * HDIM) + part * 4;
#pragma unroll
        for (int i = 0; i < 4; ++i) qv[r][i] = qp[i];
    }

    float4 acc[4][4];
    float m[4], l[4];
#pragma unroll
    for (int r = 0; r < 4; ++r) {
        m[r] = -3.0e30f; l[r] = 0.f;
#pragma unroll
        for (int i = 0; i < 4; ++i) acc[r][i] = make_float4(0.f, 0.f, 0.f, 0.f);
    }

    const int kend = qb + 255;
    for (int kb = 0; kb <= kend; kb += 64) {
        __syncthreads();
#pragma unroll
        for (int i = 0; i < 4; ++i) {
            const int e = tid + i * 256;
            const int kr = e >> 4, c = e & 15;
            const float* row = base + (size_t)(kb + kr) * C3 + h * HDIM;
            Ks[e] = ((const float4*)(row + DIM))[c];
            Vs[e] = ((const float4*)(row + 2 * DIM))[c];
        }
        __syncthreads();

        for (int j = 0; j < 64; ++j) {
            const int kj = kb + j;
            const float4* kp = &Ks[j * 16 + part * 4];
            const float4 k0 = kp[0], k1 = kp[1], k2 = kp[2], k3 = kp[3];
            float s[4];
#pragma unroll
            for (int r = 0; r < 4; ++r)
                s[r] = dot4(qv[r][0], k0) + dot4(qv[r][1], k1)
                     + dot4(qv[r][2], k2) + dot4(qv[r][3], k3);
#pragma unroll
            for (int r = 0; r < 4; ++r) {
                s[r] += __shfl_xor(s[r], 1);
                s[r] += __shfl_xor(s[r], 2);
                s[r] *= 0.125f;   // 1/sqrt(64)
            }
            const float4* vp = &Vs[j * 16 + part * 4];
            const float4 v0 = vp[0], v1 = vp[1], v2 = vp[2], v3 = vp[3];
#pragma unroll
            for (int r = 0; r < 4; ++r) {
                if (kj <= qi[r]) {
                    if (s[r] > m[r]) {
                        const float rs = __expf(m[r] - s[r]);
                        m[r] = s[r];
                        l[r] *= rs;
                        acc[r][0].x *= rs; acc[r][0].y *= rs; acc[r][0].z *= rs; acc[r][0].w *= rs;
                        acc[r][1].x *= rs; acc[r][1].y *= rs; acc[r][1].z *= rs; acc[r][1].w *= rs;
                        acc[r][2].x *= rs; acc[r][2].y *= rs; acc[r][2].z *= rs; acc[r][2].w *= rs;
                        acc[r][3].x *= rs; acc[r][3].y *= rs; acc[r][3].z *= rs; acc[r][3].w *= rs;
                    }
                    const float p = __expf(s[r] - m[r]);
                    l[r] += p;
                    acc[r][0].x += p * v0.x; acc[r][0].y += p * v0.y; acc[r][0].z += p * v0.z; acc[r][0].w += p * v0.w;
                    acc[r][1].x += p * v1.x; acc[r][1].y += p * v1.y; acc[r][1].z += p * v1.z; acc[r][1].w += p * v1.w;
                    acc[r][2].x += p * v2.x; acc[r][2].y += p * v2.y; acc[r][2].z += p * v2.z; acc[r][2].w += p * v2.w;
                    acc[r][3].x += p * v3.x; acc[r][3].y += p * v3.y; acc[r][3].z += p * v3.z; acc[r][3].w += p * v3.w;
                }
            }
        }
    }

#pragma unroll
    for (int r = 0; r < 4; ++r) {
        const float inv = 1.0f / l[r];
        float4* yp = (float4*)(y + (size_t)b * SEQ * DIM + (size_t)qi[r] * DIM + h * HDIM) + part * 4;
#pragma unroll
        for (int i = 0; i < 4; ++i) {
            const float4 o = acc[r][i];
            yp[i] = make_float4(o.x * inv, o.y * inv, o.z * inv, o.w * inv);
        }
    }
}

// ---------------------------------------------------------------------------
// Launch
// ---------------------------------------------------------------------------
extern "C" void kernel_launch(void* const* d_in, const int* in_sizes, int n_in,
                              void* d_out, int out_size, void* d_ws, size_t ws_size,
                              hipStream_t stream)
{
    const float* x      = (const float*)d_in[0];   // (2,2048,1024)
    const float* W_qkv  = (const float*)d_in[1];   // (1024,3072)
    const float* b_qkv  = (const float*)d_in[2];   // (3072,)
    const float* W_proj = (const float*)d_in[3];   // (1024,1024)
    const float* b_proj = (const float*)d_in[4];   // (1024,)
    float* out = (float*)d_out;                    // (2,2048,1024)

    char* ws = (char*)d_ws;
    float* qkv              = (float*)(ws);                          // 48 MB
    float* y                = (float*)(ws + 50331648);               // 16 MB
    unsigned short* Wqt_hi  = (unsigned short*)(ws + 67108864);      // 6 MB
    unsigned short* Wqt_lo  = (unsigned short*)(ws + 73400320);      // 6 MB
    unsigned short* Wpt_hi  = (unsigned short*)(ws + 79691776);      // 2 MB
    unsigned short* Wpt_lo  = (unsigned short*)(ws + 81788928);      // 2 MB

    const int M = BATCH * SEQ;   // 4096

    // 0) weight transpose + split
    {
        dim3 g1(3 * DIM / 32, DIM / 32);   // (96, 32)
        wt_split_kernel<<<g1, 256, 0, stream>>>(W_qkv, Wqt_hi, Wqt_lo, DIM, 3 * DIM);
        dim3 g2(DIM / 32, DIM / 32);       // (32, 32)
        wt_split_kernel<<<g2, 256, 0, stream>>>(W_proj, Wpt_hi, Wpt_lo, DIM, DIM);
    }

    // 1) QKV projection
    {
        dim3 grid(3 * DIM / 128, M / 128);   // (24, 32)
        gemm_split_kernel<<<grid, 256, 0, stream>>>(
            x, Wqt_hi, Wqt_lo, b_qkv, qkv, M, 3 * DIM, DIM);
    }

    // 2) causal attention
    {
        dim3 grid(SEQ / 256, HEADS, BATCH);  // (8, 16, 2)
        attn_kernel<<<grid, 256, 0, stream>>>(qkv, y);
    }

    // 3) output projection
    {
        dim3 grid(DIM / 128, M / 128);       // (8, 32)
        gemm_split_kernel<<<grid, 256, 0, stream>>>(
            y, Wpt_hi, Wpt_lo, b_proj, out, M, DIM, DIM);
    }
}

// Round 4
// 454.376 us; speedup vs baseline: 3.2244x; 3.2244x over previous
//
#include <hip/hip_runtime.h>
#include <math.h>

#define DIM 1024
#define HEADS 16
#define HDIM 64
#define SEQ 2048
#define BATCH 2

typedef __attribute__((ext_vector_type(8))) short short8;
typedef __attribute__((ext_vector_type(4))) float f32x4;

#define AS_K 40   // padded LDS k-stride (ushorts) for the GEMM kernel

// ---------------------------------------------------------------------------
// bf16 split helpers (round-to-nearest-even)
// ---------------------------------------------------------------------------
__device__ __forceinline__ unsigned short bf16_rtn(float x) {
    union { float f; unsigned int u; } c; c.f = x;
    unsigned int r = c.u + 0x7fffu + ((c.u >> 16) & 1u);
    return (unsigned short)(r >> 16);
}
__device__ __forceinline__ float bf16_to_f(unsigned short h) {
    union { unsigned int u; float f; } c; c.u = ((unsigned int)h) << 16;
    return c.f;
}
__device__ __forceinline__ void split_bf16(float x, unsigned short& hi, unsigned short& lo) {
    hi = bf16_rtn(x);
    lo = bf16_rtn(x - bf16_to_f(hi));
}

// ---------------------------------------------------------------------------
// Weight prep: W [K][N] f32 -> Wt_hi/Wt_lo [N][K] bf16 (transpose + split)
// ---------------------------------------------------------------------------
__global__ __launch_bounds__(256) void wt_split_kernel(
    const float* __restrict__ W, unsigned short* __restrict__ Wt_hi,
    unsigned short* __restrict__ Wt_lo, int K, int N)
{
    __shared__ float tile[32][33];
    const int k0 = blockIdx.y * 32, n0 = blockIdx.x * 32;
    const int r = threadIdx.x >> 5, c = threadIdx.x & 31;
#pragma unroll
    for (int i = 0; i < 4; ++i)
        tile[r + i * 8][c] = W[(size_t)(k0 + r + i * 8) * N + n0 + c];
    __syncthreads();
#pragma unroll
    for (int i = 0; i < 4; ++i) {
        const float v = tile[c][r + i * 8];
        unsigned short hi, lo;
        split_bf16(v, hi, lo);
        const size_t idx = (size_t)(n0 + r + i * 8) * K + k0 + c;
        Wt_hi[idx] = hi;
        Wt_lo[idx] = lo;
    }
}

// ---------------------------------------------------------------------------
// Split-bf16 MFMA GEMM (verified correct in round 2)
// ---------------------------------------------------------------------------
__global__ __launch_bounds__(256) void gemm_split_kernel(
    const float* __restrict__ A,
    const unsigned short* __restrict__ Bt_hi,
    const unsigned short* __restrict__ Bt_lo,
    const float* __restrict__ bias,
    float* __restrict__ C, int M, int N, int K)
{
    __shared__ unsigned short As_hi[128 * AS_K];
    __shared__ unsigned short As_lo[128 * AS_K];
    __shared__ unsigned short Bs_hi[128 * AS_K];
    __shared__ unsigned short Bs_lo[128 * AS_K];

    const int tid = threadIdx.x;
    const int bm = blockIdx.y * 128, bn = blockIdx.x * 128;
    const int w = tid >> 6, lane = tid & 63;
    const int wm = (w >> 1) * 64, wn = (w & 1) * 64;
    const int fr = lane & 15;
    const int ko = (lane >> 4) * 8;

    const int ar = tid >> 1, ac = (tid & 1) * 16;
    const float* ap = A + (size_t)(bm + ar) * K + ac;
    const unsigned short* bph = Bt_hi + (size_t)(bn + ar) * K + ac;
    const unsigned short* bpl = Bt_lo + (size_t)(bn + ar) * K + ac;

    f32x4 acc[4][4];
#pragma unroll
    for (int i = 0; i < 4; ++i)
#pragma unroll
        for (int j = 0; j < 4; ++j)
            acc[i][j] = (f32x4){0.f, 0.f, 0.f, 0.f};

    float4 av[4];
    float4 bh[2], bl[2];

#pragma unroll
    for (int i = 0; i < 4; ++i) av[i] = ((const float4*)ap)[i];
    bh[0] = ((const float4*)bph)[0]; bh[1] = ((const float4*)bph)[1];
    bl[0] = ((const float4*)bpl)[0]; bl[1] = ((const float4*)bpl)[1];

    const int nsteps = K / 32;
    for (int s = 0; s < nsteps; ++s) {
        __syncthreads();
        {
            unsigned int hw[8], lw[8];
            const float* af = (const float*)av;
#pragma unroll
            for (int i = 0; i < 8; ++i) {
                unsigned short h0, l0, h1, l1;
                split_bf16(af[2 * i], h0, l0);
                split_bf16(af[2 * i + 1], h1, l1);
                hw[i] = (unsigned int)h0 | ((unsigned int)h1 << 16);
                lw[i] = (unsigned int)l0 | ((unsigned int)l1 << 16);
            }
            unsigned int* dh = (unsigned int*)&As_hi[ar * AS_K + ac];
            unsigned int* dl = (unsigned int*)&As_lo[ar * AS_K + ac];
            *(uint4*)(dh + 0) = *(uint4*)&hw[0];
            *(uint4*)(dh + 4) = *(uint4*)&hw[4];
            *(uint4*)(dl + 0) = *(uint4*)&lw[0];
            *(uint4*)(dl + 4) = *(uint4*)&lw[4];
        }
        {
            unsigned int* dh = (unsigned int*)&Bs_hi[ar * AS_K + ac];
            unsigned int* dl = (unsigned int*)&Bs_lo[ar * AS_K + ac];
            *(uint4*)(dh + 0) = *(uint4*)&bh[0];
            *(uint4*)(dh + 4) = *(uint4*)&bh[1];
            *(uint4*)(dl + 0) = *(uint4*)&bl[0];
            *(uint4*)(dl + 4) = *(uint4*)&bl[1];
        }
        __syncthreads();

        if (s + 1 < nsteps) {
            const int k0 = (s + 1) * 32;
#pragma unroll
            for (int i = 0; i < 4; ++i) av[i] = ((const float4*)(ap + k0))[i];
            bh[0] = ((const float4*)(bph + k0))[0]; bh[1] = ((const float4*)(bph + k0))[1];
            bl[0] = ((const float4*)(bpl + k0))[0]; bl[1] = ((const float4*)(bpl + k0))[1];
        }

        short8 a_hi[4], a_lo[4], b_hi[4], b_lo[4];
#pragma unroll
        for (int f = 0; f < 4; ++f) {
            const int arow = (wm + f * 16 + fr) * AS_K + ko;
            a_hi[f] = *(const short8*)&As_hi[arow];
            a_lo[f] = *(const short8*)&As_lo[arow];
            const int brow = (wn + f * 16 + fr) * AS_K + ko;
            b_hi[f] = *(const short8*)&Bs_hi[brow];
            b_lo[f] = *(const short8*)&Bs_lo[brow];
        }
#pragma unroll
        for (int fm = 0; fm < 4; ++fm)
#pragma unroll
            for (int fn = 0; fn < 4; ++fn) {
                f32x4 c = acc[fm][fn];
                c = __builtin_amdgcn_mfma_f32_16x16x32_bf16(a_hi[fm], b_hi[fn], c, 0, 0, 0);
                c = __builtin_amdgcn_mfma_f32_16x16x32_bf16(a_hi[fm], b_lo[fn], c, 0, 0, 0);
                c = __builtin_amdgcn_mfma_f32_16x16x32_bf16(a_lo[fm], b_hi[fn], c, 0, 0, 0);
                acc[fm][fn] = c;
            }
    }

    float bv[4];
#pragma unroll
    for (int fn = 0; fn < 4; ++fn) bv[fn] = bias[bn + wn + fn * 16 + fr];
#pragma unroll
    for (int fm = 0; fm < 4; ++fm) {
        const int row0 = bm + wm + fm * 16 + (lane >> 4) * 4;
#pragma unroll
        for (int fn = 0; fn < 4; ++fn) {
            const int col = bn + wn + fn * 16 + fr;
#pragma unroll
            for (int r = 0; r < 4; ++r)
                C[(size_t)(row0 + r) * N + col] = acc[fm][fn][r] + bv[fn];
        }
    }
}

// ---------------------------------------------------------------------------
// MFMA flash attention (causal), split-bf16 3-term for QK^T and PV.
//
// Block: 256 thr = 4 waves; QBLK=128 (32 q/wave); KBLK=64.
// Swapped QK^T: S^T = mfma(A=K, B=Q) -> per lane: q col = lane&15, keys in regs.
// LDS frag-major layout: fragment for (frag,g,c) lives at slot*16B,
// slot = frag*64 + g*16 + c  ==> all b128 LDS ops are lane-linear (no conflicts).
// P (hi/lo) overwrites K's LDS after QK^T (barrier-separated). LDS = 48 KB.
// ---------------------------------------------------------------------------
__global__ __launch_bounds__(256) void attn_mfma_kernel(
    const float* __restrict__ qkv, float* __restrict__ y)
{
    __shared__ __align__(16) char smem[49152];
    unsigned short* Kh = (unsigned short*)smem;              // 8K (later P of wave 0)
    unsigned short* Kl = (unsigned short*)(smem + 8192);     // 8K (later P of wave 1)
    unsigned short* Vh = (unsigned short*)(smem + 16384);    // 8K
    unsigned short* Vl = (unsigned short*)(smem + 24576);    // 8K

    const int tid = threadIdx.x;
    const int w = tid >> 6, lane = tid & 63;
    const int c = lane & 15;      // frag col
    const int g = lane >> 4;      // frag k-group
    const int C3 = 3 * DIM;

    const int tilemax = (int)gridDim.x - 1;
    const int tile = blockIdx.z ? (int)blockIdx.x : (tilemax - (int)blockIdx.x);
    const int qb = tile * 128;
    const int h = blockIdx.y, b = blockIdx.z;
    const int qw = qb + 32 * w;

    char* Pw = (w < 2) ? (smem + 8192 * w) : (smem + 32768 + 8192 * (w - 2));
    unsigned short* Ph = (unsigned short*)Pw;            // 4K
    unsigned short* Pl = (unsigned short*)(Pw + 4096);   // 4K

    const float* base = qkv + (size_t)b * SEQ * C3;

    // ---- Q fragments in registers (scaled by 1/sqrt(64), split hi/lo) ----
    short8 q_hi[2][2], q_lo[2][2];
#pragma unroll
    for (int nf = 0; nf < 2; ++nf)
#pragma unroll
        for (int kf = 0; kf < 2; ++kf) {
            const int row = qw + 16 * nf + c;
            const int d0 = 32 * kf + 8 * g;
            const float4* qp = (const float4*)(base + (size_t)row * C3 + h * HDIM + d0);
            float4 f0 = qp[0], f1 = qp[1];
            float tf[8] = {f0.x, f0.y, f0.z, f0.w, f1.x, f1.y, f1.z, f1.w};
#pragma unroll
            for (int j = 0; j < 8; ++j) {
                unsigned short hh, ll;
                split_bf16(tf[j] * 0.125f, hh, ll);
                q_hi[nf][kf][j] = (short)hh;
                q_lo[nf][kf][j] = (short)ll;
            }
        }

    f32x4 o[2][4];
#pragma unroll
    for (int i = 0; i < 2; ++i)
#pragma unroll
        for (int j = 0; j < 4; ++j) o[i][j] = (f32x4){0.f, 0.f, 0.f, 0.f};
    float m_run[2] = {-3.0e30f, -3.0e30f};
    float l_run[2] = {0.f, 0.f};

    const int nch = qb / 64 + 2;
    for (int ch = 0; ch < nch; ++ch) {
        const int kb = ch * 64;
        __syncthreads();   // B1: prior chunk's LDS reads done

        // ---- stage K (hi/lo) into frag-major slots ----
#pragma unroll
        for (int i = 0; i < 2; ++i) {
            const int s = tid + 256 * i;
            const int sc = s & 15, sg = (s >> 4) & 3, skf = (s >> 6) & 1, smf = s >> 7;
            const int row = kb + 16 * smf + sc;
            const int d0 = 32 * skf + 8 * sg;
            const float4* kp = (const float4*)(base + (size_t)row * C3 + DIM + h * HDIM + d0);
            float4 f0 = kp[0], f1 = kp[1];
            float tf[8] = {f0.x, f0.y, f0.z, f0.w, f1.x, f1.y, f1.z, f1.w};
            unsigned int hw[4], lw[4];
#pragma unroll
            for (int j = 0; j < 4; ++j) {
                unsigned short h0, l0, h1, l1;
                split_bf16(tf[2 * j], h0, l0);
                split_bf16(tf[2 * j + 1], h1, l1);
                hw[j] = (unsigned int)h0 | ((unsigned int)h1 << 16);
                lw[j] = (unsigned int)l0 | ((unsigned int)l1 << 16);
            }
            *(uint4*)((char*)Kh + s * 16) = *(uint4*)hw;
            *(uint4*)((char*)Kl + s * 16) = *(uint4*)lw;
        }
        // ---- stage V^T (hi/lo): key-pairs packed as u32 into frag-major slots ----
#pragma unroll
        for (int i = 0; i < 2; ++i) {
            const int s2 = tid + 256 * i;
            const int rp = s2 >> 4, c4 = s2 & 15;
            const float* r0 = base + (size_t)(kb + 2 * rp) * C3 + 2 * DIM + h * HDIM + 4 * c4;
            const float* r1 = r0 + C3;
            float4 a = *(const float4*)r0;
            float4 bq = *(const float4*)r1;
            const float* af = (const float*)&a;
            const float* bf = (const float*)&bq;
            const int kf = rp >> 4, gg = (rp >> 2) & 3, joff = 4 * (rp & 3);
#pragma unroll
            for (int ii = 0; ii < 4; ++ii) {
                const int d = 4 * c4 + ii;
                const int slot = (((d >> 4) * 2 + kf) * 4 + gg) * 16 + (d & 15);
                unsigned short h0, l0, h1, l1;
                split_bf16(af[ii], h0, l0);
                split_bf16(bf[ii], h1, l1);
                *(unsigned int*)((char*)Vh + slot * 16 + joff) = (unsigned int)h0 | ((unsigned int)h1 << 16);
                *(unsigned int*)((char*)Vl + slot * 16 + joff) = (unsigned int)l0 | ((unsigned int)l1 << 16);
            }
        }
        __syncthreads();   // B2: staging visible

        const bool active = (kb <= qw + 31);
        const bool diag = active && (kb + 63 > qw);
        f32x4 st[4][2];
        float fscale[2];

        if (active) {
            // ---- S^T = K * Q^T (split 3-term) ----
#pragma unroll
            for (int mf = 0; mf < 4; ++mf)
#pragma unroll
                for (int nf = 0; nf < 2; ++nf) st[mf][nf] = (f32x4){0.f, 0.f, 0.f, 0.f};
#pragma unroll
            for (int kf = 0; kf < 2; ++kf)
#pragma unroll
                for (int mf = 0; mf < 4; ++mf) {
                    const int slot = ((mf * 2 + kf) * 4 + g) * 16 + c;
                    short8 ah = *(const short8*)((const char*)Kh + slot * 16);
                    short8 al = *(const short8*)((const char*)Kl + slot * 16);
#pragma unroll
                    for (int nf = 0; nf < 2; ++nf) {
                        st[mf][nf] = __builtin_amdgcn_mfma_f32_16x16x32_bf16(ah, q_hi[nf][kf], st[mf][nf], 0, 0, 0);
                        st[mf][nf] = __builtin_amdgcn_mfma_f32_16x16x32_bf16(ah, q_lo[nf][kf], st[mf][nf], 0, 0, 0);
                        st[mf][nf] = __builtin_amdgcn_mfma_f32_16x16x32_bf16(al, q_hi[nf][kf], st[mf][nf], 0, 0, 0);
                    }
                }
            // ---- mask + online softmax state ----
#pragma unroll
            for (int nf = 0; nf < 2; ++nf) {
                float cm = -3.0e30f;
#pragma unroll
                for (int mf = 0; mf < 4; ++mf)
#pragma unroll
                    for (int r = 0; r < 4; ++r) {
                        float s = st[mf][nf][r];
                        if (diag && (kb + 16 * mf + 4 * g + r > qw + 16 * nf + c)) s = -3.0e30f;
                        st[mf][nf][r] = s;
                        cm = fmaxf(cm, s);
                    }
                cm = fmaxf(cm, __shfl_xor(cm, 16));
                cm = fmaxf(cm, __shfl_xor(cm, 32));
                const float mnew = fmaxf(m_run[nf], cm);
                fscale[nf] = __expf(m_run[nf] - mnew);
                m_run[nf] = mnew;
                l_run[nf] *= fscale[nf];
            }
            // ---- O rescale ----
#pragma unroll
            for (int mf = 0; mf < 2; ++mf)
#pragma unroll
                for (int r = 0; r < 4; ++r) {
                    const float fo = __shfl(fscale[mf], 4 * g + r);
#pragma unroll
                    for (int nf = 0; nf < 4; ++nf) o[mf][nf][r] *= fo;
                }
        }
        __syncthreads();   // B3: all K reads done; P may overwrite K space

        if (active) {
            // ---- P = exp(S - m), split hi/lo, frag-major P slots ----
#pragma unroll
            for (int nf = 0; nf < 2; ++nf) {
#pragma unroll
                for (int mf = 0; mf < 4; ++mf) {
                    const int slot = ((nf * 2 + (mf >> 1)) * 4 + ((2 * mf + (g >> 1)) & 3)) * 16 + c;
                    const int bofs = slot * 16 + 8 * (g & 1);
#pragma unroll
                    for (int k = 0; k < 2; ++k) {
                        const float p0 = __expf(st[mf][nf][2 * k] - m_run[nf]);
                        const float p1 = __expf(st[mf][nf][2 * k + 1] - m_run[nf]);
                        l_run[nf] += p0 + p1;
                        unsigned short h0, l0, h1, l1;
                        split_bf16(p0, h0, l0);
                        split_bf16(p1, h1, l1);
                        *(unsigned int*)((char*)Ph + bofs + 4 * k) = (unsigned int)h0 | ((unsigned int)h1 << 16);
                        *(unsigned int*)((char*)Pl + bofs + 4 * k) = (unsigned int)l0 | ((unsigned int)l1 << 16);
                    }
                }
            }
            // ---- O += P * V (split 3-term) ----
#pragma unroll
            for (int kf = 0; kf < 2; ++kf) {
                short8 pa_h[2], pa_l[2];
#pragma unroll
                for (int mf = 0; mf < 2; ++mf) {
                    const int slot = ((mf * 2 + kf) * 4 + g) * 16 + c;
                    pa_h[mf] = *(const short8*)((const char*)Ph + slot * 16);
                    pa_l[mf] = *(const short8*)((const char*)Pl + slot * 16);
                }
#pragma unroll
                for (int nf = 0; nf < 4; ++nf) {
                    const int slot = ((nf * 2 + kf) * 4 + g) * 16 + c;
                    short8 vb_h = *(const short8*)((const char*)Vh + slot * 16);
                    short8 vb_l = *(const short8*)((const char*)Vl + slot * 16);
#pragma unroll
                    for (int mf = 0; mf < 2; ++mf) {
                        o[mf][nf] = __builtin_amdgcn_mfma_f32_16x16x32_bf16(pa_h[mf], vb_h, o[mf][nf], 0, 0, 0);
                        o[mf][nf] = __builtin_amdgcn_mfma_f32_16x16x32_bf16(pa_h[mf], vb_l, o[mf][nf], 0, 0, 0);
                        o[mf][nf] = __builtin_amdgcn_mfma_f32_16x16x32_bf16(pa_l[mf], vb_h, o[mf][nf], 0, 0, 0);
                    }
                }
            }
        }
    }

    // ---- finalize: l reduction, normalize, store ----
    float linv[2];
#pragma unroll
    for (int nf = 0; nf < 2; ++nf) {
        float lt = l_run[nf];
        lt += __shfl_xor(lt, 16);
        lt += __shfl_xor(lt, 32);
        linv[nf] = 1.0f / lt;
    }
#pragma unroll
    for (int mf = 0; mf < 2; ++mf)
#pragma unroll
        for (int r = 0; r < 4; ++r) {
            const float li = __shfl(linv[mf], 4 * g + r);
            const int row = qw + 16 * mf + 4 * g + r;
            float* yp = y + ((size_t)b * SEQ + row) * DIM + h * HDIM + c;
#pragma unroll
            for (int nf = 0; nf < 4; ++nf)
                yp[16 * nf] = o[mf][nf][r] * li;
        }
}

// ---------------------------------------------------------------------------
// Launch
// ---------------------------------------------------------------------------
extern "C" void kernel_launch(void* const* d_in, const int* in_sizes, int n_in,
                              void* d_out, int out_size, void* d_ws, size_t ws_size,
                              hipStream_t stream)
{
    const float* x      = (const float*)d_in[0];
    const float* W_qkv  = (const float*)d_in[1];
    const float* b_qkv  = (const float*)d_in[2];
    const float* W_proj = (const float*)d_in[3];
    const float* b_proj = (const float*)d_in[4];
    float* out = (float*)d_out;

    char* ws = (char*)d_ws;
    float* qkv              = (float*)(ws);                          // 48 MB
    float* y                = (float*)(ws + 50331648);               // 16 MB
    unsigned short* Wqt_hi  = (unsigned short*)(ws + 67108864);
    unsigned short* Wqt_lo  = (unsigned short*)(ws + 73400320);
    unsigned short* Wpt_hi  = (unsigned short*)(ws + 79691776);
    unsigned short* Wpt_lo  = (unsigned short*)(ws + 81788928);

    const int M = BATCH * SEQ;

    {
        dim3 g1(3 * DIM / 32, DIM / 32);
        wt_split_kernel<<<g1, 256, 0, stream>>>(W_qkv, Wqt_hi, Wqt_lo, DIM, 3 * DIM);
        dim3 g2(DIM / 32, DIM / 32);
        wt_split_kernel<<<g2, 256, 0, stream>>>(W_proj, Wpt_hi, Wpt_lo, DIM, DIM);
    }
    {
        dim3 grid(3 * DIM / 128, M / 128);
        gemm_split_kernel<<<grid, 256, 0, stream>>>(
            x, Wqt_hi, Wqt_lo, b_qkv, qkv, M, 3 * DIM, DIM);
    }
    {
        dim3 grid(SEQ / 128, HEADS, BATCH);   // (16,16,2)
        attn_mfma_kernel<<<grid, 256, 0, stream>>>(qkv, y);
    }
    {
        dim3 grid(DIM / 128, M / 128);
        gemm_split_kernel<<<grid, 256, 0, stream>>>(
            y, Wpt_hi, Wpt_lo, b_proj, out, M, DIM, DIM);
    }
}

// Round 7
// 348.748 us; speedup vs baseline: 4.2010x; 1.3029x over previous
//
#include <hip/hip_runtime.h>
#include <math.h>

#define DIM 1024
#define HEADS 16
#define HDIM 64
#define SEQ 2048
#define BATCH 2

typedef __attribute__((ext_vector_type(8))) short short8;
typedef __attribute__((ext_vector_type(4))) float f32x4;

// ---------------------------------------------------------------------------
// bf16 split helpers (round-to-nearest-even)
// ---------------------------------------------------------------------------
__device__ __forceinline__ unsigned short bf16_rtn(float x) {
    union { float f; unsigned int u; } c; c.f = x;
    unsigned int r = c.u + 0x7fffu + ((c.u >> 16) & 1u);
    return (unsigned short)(r >> 16);
}
__device__ __forceinline__ float bf16_to_f(unsigned short h) {
    union { unsigned int u; float f; } c; c.u = ((unsigned int)h) << 16;
    return c.f;
}
__device__ __forceinline__ void split_bf16(float x, unsigned short& hi, unsigned short& lo) {
    hi = bf16_rtn(x);
    lo = bf16_rtn(x - bf16_to_f(hi));
}

// ---------------------------------------------------------------------------
// prep_a: A f32 [M][K] -> Ah/Al bf16 frag-major units.
// Unit (mu,ku) = 1KB: [g=4][c=16][e=8] ushorts; element = A[mu*16+c][ku*32+g*8+e].
// grid = M/16 blocks, 256 threads.
// ---------------------------------------------------------------------------
__global__ __launch_bounds__(256) void prep_a_kernel(
    const float* __restrict__ A, unsigned short* __restrict__ Ah,
    unsigned short* __restrict__ Al, int K)
{
    const int mu = blockIdx.x;
    const int nku = K >> 5;
    const int t = threadIdx.x;
    const int c = t & 15;
    const int pb = t >> 4;
    const int npairs = K >> 3;
    for (int p = pb; p < npairs; p += 16) {
        const int ku = p >> 2, g = p & 3;
        const float* src = A + (size_t)(mu * 16 + c) * K + ku * 32 + g * 8;
        const float4 f0 = ((const float4*)src)[0];
        const float4 f1 = ((const float4*)src)[1];
        const float tf[8] = {f0.x, f0.y, f0.z, f0.w, f1.x, f1.y, f1.z, f1.w};
        unsigned int hw[4], lw[4];
#pragma unroll
        for (int j = 0; j < 4; ++j) {
            unsigned short h0, l0, h1, l1;
            split_bf16(tf[2 * j], h0, l0);
            split_bf16(tf[2 * j + 1], h1, l1);
            hw[j] = (unsigned int)h0 | ((unsigned int)h1 << 16);
            lw[j] = (unsigned int)l0 | ((unsigned int)l1 << 16);
        }
        const size_t off = ((size_t)mu * nku + ku) * 512 + g * 128 + c * 8;
        *(uint4*)(Ah + off) = *(uint4*)hw;
        *(uint4*)(Al + off) = *(uint4*)lw;
    }
}

// ---------------------------------------------------------------------------
// prep_w: W f32 [K][N] -> Wh/Wl frag-major units over (nu,ku) (transposed).
// Unit element (g,c,e) = W[ku*32+g*8+e][nu*16+c].  grid = N/16 blocks.
// ---------------------------------------------------------------------------
__global__ __launch_bounds__(256) void prep_w_kernel(
    const float* __restrict__ W, unsigned short* __restrict__ Wh,
    unsigned short* __restrict__ Wl, int K, int N)
{
    const int nu = blockIdx.x;
    const int nku = K >> 5;
    const int t = threadIdx.x;
    const int c = t & 15;
    const int pb = t >> 4;
    const int npairs = K >> 3;
    for (int p = pb; p < npairs; p += 16) {
        const int ku = p >> 2, g = p & 3;
        unsigned int hw[4], lw[4];
#pragma unroll
        for (int j = 0; j < 4; ++j) {
            const float v0 = W[(size_t)(ku * 32 + g * 8 + 2 * j) * N + nu * 16 + c];
            const float v1 = W[(size_t)(ku * 32 + g * 8 + 2 * j + 1) * N + nu * 16 + c];
            unsigned short h0, l0, h1, l1;
            split_bf16(v0, h0, l0);
            split_bf16(v1, h1, l1);
            hw[j] = (unsigned int)h0 | ((unsigned int)h1 << 16);
            lw[j] = (unsigned int)l0 | ((unsigned int)l1 << 16);
        }
        const size_t off = ((size_t)nu * nku + ku) * 512 + g * 128 + c * 8;
        *(uint4*)(Wh + off) = *(uint4*)hw;
        *(uint4*)(Wl + off) = *(uint4*)lw;
    }
}

// ---------------------------------------------------------------------------
// Split-bf16 MFMA GEMM on frag-major inputs.
// C[m][n] = sum_k A[m][k]*B^T[n][k] + bias[n], 3-term split (AhBh+AhBl+AlBh).
// BM=BN=128, BK=32, 256 thr (4 waves 2x2, 64x64/wave).
// Transposed accumulators (mfma(b,a)) -> lane holds one row x 4 consecutive
// cols -> float4 coalesced epilogue. All LDS ops lane-linear (conflict-free).
// ---------------------------------------------------------------------------
__global__ __launch_bounds__(256) void gemm_frag(
    const unsigned short* __restrict__ Ah, const unsigned short* __restrict__ Al,
    const unsigned short* __restrict__ Bh, const unsigned short* __restrict__ Bl,
    const float* __restrict__ bias, float* __restrict__ C,
    int M, int N, int K)
{
    __shared__ __align__(16) unsigned short sm[16384];   // 32 KB: 32 units x 1KB
    const int nku = K >> 5;
    const int tid = threadIdx.x;
    const int w = tid >> 6, lane = tid & 63;
    const int c = lane & 15, g = lane >> 4;
    const int bm = blockIdx.y * 128, bn = blockIdx.x * 128;
    const int wm = (w >> 1) * 64, wn = (w & 1) * 64;

    // staging: 8 x 16B granules per thread; luid 0..31 = [Ah 0-7|Al 8-15|Bh 16-23|Bl 24-31]
    const unsigned short* srcp[8];
    int dsto[8];
#pragma unroll
    for (int i = 0; i < 8; ++i) {
        const int flat = i * 256 + tid;
        const int luid = flat >> 6, gran = flat & 63;
        const int buf = luid >> 3, uloc = luid & 7;
        const unsigned short* base = (buf == 0) ? Ah : (buf == 1) ? Al : (buf == 2) ? Bh : Bl;
        const int rb = (buf < 2) ? bm : bn;
        srcp[i] = base + ((size_t)(rb / 16 + uloc) * nku) * 512 + gran * 8;
        dsto[i] = flat * 8;
    }

    f32x4 acc[4][4];
#pragma unroll
    for (int i = 0; i < 4; ++i)
#pragma unroll
        for (int j = 0; j < 4; ++j) acc[i][j] = (f32x4){0.f, 0.f, 0.f, 0.f};

    short8 nxt[8];
#pragma unroll
    for (int i = 0; i < 8; ++i) nxt[i] = *(const short8*)(srcp[i]);

    for (int ks = 0; ks < nku; ++ks) {
        __syncthreads();
#pragma unroll
        for (int i = 0; i < 8; ++i) *(short8*)(sm + dsto[i]) = nxt[i];
        __syncthreads();

        if (ks + 1 < nku) {
            const int off = (ks + 1) * 512;
#pragma unroll
            for (int i = 0; i < 8; ++i) nxt[i] = *(const short8*)(srcp[i] + off);
        }

        short8 ahf[4], alf[4], bhf[4], blf[4];
        const int lo = lane * 8;
#pragma unroll
        for (int f = 0; f < 4; ++f) {
            ahf[f] = *(const short8*)(sm + (wm / 16 + f) * 512 + lo);
            alf[f] = *(const short8*)(sm + (8 + wm / 16 + f) * 512 + lo);
            bhf[f] = *(const short8*)(sm + (16 + wn / 16 + f) * 512 + lo);
            blf[f] = *(const short8*)(sm + (24 + wn / 16 + f) * 512 + lo);
        }
#pragma unroll
        for (int fm = 0; fm < 4; ++fm)
#pragma unroll
            for (int fn = 0; fn < 4; ++fn) {
                f32x4 cc = acc[fm][fn];
                cc = __builtin_amdgcn_mfma_f32_16x16x32_bf16(bhf[fn], ahf[fm], cc, 0, 0, 0);
                cc = __builtin_amdgcn_mfma_f32_16x16x32_bf16(blf[fn], ahf[fm], cc, 0, 0, 0);
                cc = __builtin_amdgcn_mfma_f32_16x16x32_bf16(bhf[fn], alf[fm], cc, 0, 0, 0);
                acc[fm][fn] = cc;
            }
    }

    // epilogue: acc[fm][fn][r] = C[bm+wm+fm*16+c][bn+wn+fn*16+4g+r]
    float4 bv[4];
#pragma unroll
    for (int fn = 0; fn < 4; ++fn)
        bv[fn] = *(const float4*)&bias[bn + wn + fn * 16 + 4 * g];
#pragma unroll
    for (int fm = 0; fm < 4; ++fm) {
        const int row = bm + wm + fm * 16 + c;
        float* cp = C + (size_t)row * N + bn + wn + 4 * g;
#pragma unroll
        for (int fn = 0; fn < 4; ++fn) {
            float4 o;
            o.x = acc[fm][fn][0] + bv[fn].x;
            o.y = acc[fm][fn][1] + bv[fn].y;
            o.z = acc[fm][fn][2] + bv[fn].z;
            o.w = acc[fm][fn][3] + bv[fn].w;
            *(float4*)(cp + fn * 16) = o;
        }
    }
}

// ---------------------------------------------------------------------------
// MFMA flash attention (causal), split-bf16 3-term; transposed PV accumulator
// (mfma(V^T, P)) -> lane holds one query row x 4 consecutive dims -> no shfl
// in rescale/normalize, float4 coalesced y stores.
// ---------------------------------------------------------------------------
__global__ __launch_bounds__(256) void attn_mfma_kernel(
    const float* __restrict__ qkv, float* __restrict__ y)
{
    __shared__ __align__(16) char smem[49152];
    unsigned short* Kh = (unsigned short*)smem;              // 8K (later P of wave 0)
    unsigned short* Kl = (unsigned short*)(smem + 8192);     // 8K (later P of wave 1)
    unsigned short* Vh = (unsigned short*)(smem + 16384);    // 8K
    unsigned short* Vl = (unsigned short*)(smem + 24576);    // 8K

    const int tid = threadIdx.x;
    const int w = tid >> 6, lane = tid & 63;
    const int c = lane & 15;      // frag col
    const int g = lane >> 4;      // frag k-group
    const int C3 = 3 * DIM;

    const int tilemax = (int)gridDim.x - 1;
    const int tile = blockIdx.z ? (int)blockIdx.x : (tilemax - (int)blockIdx.x);
    const int qb = tile * 128;
    const int h = blockIdx.y, b = blockIdx.z;
    const int qw = qb + 32 * w;

    char* Pw = (w < 2) ? (smem + 8192 * w) : (smem + 32768 + 8192 * (w - 2));
    unsigned short* Ph = (unsigned short*)Pw;            // 4K
    unsigned short* Pl = (unsigned short*)(Pw + 4096);   // 4K

    const float* base = qkv + (size_t)b * SEQ * C3;

    // ---- Q fragments in registers (scaled by 1/sqrt(64), split hi/lo) ----
    short8 q_hi[2][2], q_lo[2][2];
#pragma unroll
    for (int nf = 0; nf < 2; ++nf)
#pragma unroll
        for (int kf = 0; kf < 2; ++kf) {
            const int row = qw + 16 * nf + c;
            const int d0 = 32 * kf + 8 * g;
            const float4* qp = (const float4*)(base + (size_t)row * C3 + h * HDIM + d0);
            float4 f0 = qp[0], f1 = qp[1];
            float tf[8] = {f0.x, f0.y, f0.z, f0.w, f1.x, f1.y, f1.z, f1.w};
#pragma unroll
            for (int j = 0; j < 8; ++j) {
                unsigned short hh, ll;
                split_bf16(tf[j] * 0.125f, hh, ll);
                q_hi[nf][kf][j] = (short)hh;
                q_lo[nf][kf][j] = (short)ll;
            }
        }

    f32x4 o[2][4];
#pragma unroll
    for (int i = 0; i < 2; ++i)
#pragma unroll
        for (int j = 0; j < 4; ++j) o[i][j] = (f32x4){0.f, 0.f, 0.f, 0.f};
    float m_run[2] = {-3.0e30f, -3.0e30f};
    float l_run[2] = {0.f, 0.f};

    const int nch = qb / 64 + 2;
    for (int ch = 0; ch < nch; ++ch) {
        const int kb = ch * 64;
        __syncthreads();   // B1: prior chunk's LDS reads done

        // ---- stage K (hi/lo) into frag-major slots ----
#pragma unroll
        for (int i = 0; i < 2; ++i) {
            const int s = tid + 256 * i;
            const int sc = s & 15, sg = (s >> 4) & 3, skf = (s >> 6) & 1, smf = s >> 7;
            const int row = kb + 16 * smf + sc;
            const int d0 = 32 * skf + 8 * sg;
            const float4* kp = (const float4*)(base + (size_t)row * C3 + DIM + h * HDIM + d0);
            float4 f0 = kp[0], f1 = kp[1];
            float tf[8] = {f0.x, f0.y, f0.z, f0.w, f1.x, f1.y, f1.z, f1.w};
            unsigned int hw[4], lw[4];
#pragma unroll
            for (int j = 0; j < 4; ++j) {
                unsigned short h0, l0, h1, l1;
                split_bf16(tf[2 * j], h0, l0);
                split_bf16(tf[2 * j + 1], h1, l1);
                hw[j] = (unsigned int)h0 | ((unsigned int)h1 << 16);
                lw[j] = (unsigned int)l0 | ((unsigned int)l1 << 16);
            }
            *(uint4*)((char*)Kh + s * 16) = *(uint4*)hw;
            *(uint4*)((char*)Kl + s * 16) = *(uint4*)lw;
        }
        // ---- stage V^T (hi/lo): key-pairs packed as u32 into frag-major slots ----
#pragma unroll
        for (int i = 0; i < 2; ++i) {
            const int s2 = tid + 256 * i;
            const int rp = s2 >> 4, c4 = s2 & 15;
            const float* r0 = base + (size_t)(kb + 2 * rp) * C3 + 2 * DIM + h * HDIM + 4 * c4;
            const float* r1 = r0 + C3;
            float4 a = *(const float4*)r0;
            float4 bq = *(const float4*)r1;
            const float* af = (const float*)&a;
            const float* bf = (const float*)&bq;
            const int kf = rp >> 4, gg = (rp >> 2) & 3, joff = 4 * (rp & 3);
#pragma unroll
            for (int ii = 0; ii < 4; ++ii) {
                const int d = 4 * c4 + ii;
                const int slot = (((d >> 4) * 2 + kf) * 4 + gg) * 16 + (d & 15);
                unsigned short h0, l0, h1, l1;
                split_bf16(af[ii], h0, l0);
                split_bf16(bf[ii], h1, l1);
                *(unsigned int*)((char*)Vh + slot * 16 + joff) = (unsigned int)h0 | ((unsigned int)h1 << 16);
                *(unsigned int*)((char*)Vl + slot * 16 + joff) = (unsigned int)l0 | ((unsigned int)l1 << 16);
            }
        }
        __syncthreads();   // B2: staging visible

        const bool active = (kb <= qw + 31);
        const bool diag = active && (kb + 63 > qw);
        f32x4 st[4][2];
        float fscale[2];

        if (active) {
            // ---- S^T = K * Q^T (split 3-term) ----
#pragma unroll
            for (int mf = 0; mf < 4; ++mf)
#pragma unroll
                for (int nf = 0; nf < 2; ++nf) st[mf][nf] = (f32x4){0.f, 0.f, 0.f, 0.f};
#pragma unroll
            for (int kf = 0; kf < 2; ++kf)
#pragma unroll
                for (int mf = 0; mf < 4; ++mf) {
                    const int slot = ((mf * 2 + kf) * 4 + g) * 16 + c;
                    short8 ah = *(const short8*)((const char*)Kh + slot * 16);
                    short8 al = *(const short8*)((const char*)Kl + slot * 16);
#pragma unroll
                    for (int nf = 0; nf < 2; ++nf) {
                        st[mf][nf] = __builtin_amdgcn_mfma_f32_16x16x32_bf16(ah, q_hi[nf][kf], st[mf][nf], 0, 0, 0);
                        st[mf][nf] = __builtin_amdgcn_mfma_f32_16x16x32_bf16(ah, q_lo[nf][kf], st[mf][nf], 0, 0, 0);
                        st[mf][nf] = __builtin_amdgcn_mfma_f32_16x16x32_bf16(al, q_hi[nf][kf], st[mf][nf], 0, 0, 0);
                    }
                }
            // ---- mask + online softmax state ----
#pragma unroll
            for (int nf = 0; nf < 2; ++nf) {
                float cm = -3.0e30f;
#pragma unroll
                for (int mf = 0; mf < 4; ++mf)
#pragma unroll
                    for (int r = 0; r < 4; ++r) {
                        float s = st[mf][nf][r];
                        if (diag && (kb + 16 * mf + 4 * g + r > qw + 16 * nf + c)) s = -3.0e30f;
                        st[mf][nf][r] = s;
                        cm = fmaxf(cm, s);
                    }
                cm = fmaxf(cm, __shfl_xor(cm, 16));
                cm = fmaxf(cm, __shfl_xor(cm, 32));
                const float mnew = fmaxf(m_run[nf], cm);
                fscale[nf] = __expf(m_run[nf] - mnew);
                m_run[nf] = mnew;
                l_run[nf] *= fscale[nf];
            }
            // ---- O rescale (transposed acc: whole f32x4 is one query) ----
#pragma unroll
            for (int mf = 0; mf < 2; ++mf) {
                const float fo = fscale[mf];
#pragma unroll
                for (int nf = 0; nf < 4; ++nf) {
                    o[mf][nf][0] *= fo; o[mf][nf][1] *= fo;
                    o[mf][nf][2] *= fo; o[mf][nf][3] *= fo;
                }
            }
        }
        __syncthreads();   // B3: all K reads done; P may overwrite K space

        if (active) {
            // ---- P = exp(S - m), split hi/lo, frag-major P slots ----
#pragma unroll
            for (int nf = 0; nf < 2; ++nf) {
#pragma unroll
                for (int mf = 0; mf < 4; ++mf) {
                    const int slot = ((nf * 2 + (mf >> 1)) * 4 + ((2 * mf + (g >> 1)) & 3)) * 16 + c;
                    const int bofs = slot * 16 + 8 * (g & 1);
#pragma unroll
                    for (int k = 0; k < 2; ++k) {
                        const float p0 = __expf(st[mf][nf][2 * k] - m_run[nf]);
                        const float p1 = __expf(st[mf][nf][2 * k + 1] - m_run[nf]);
                        l_run[nf] += p0 + p1;
                        unsigned short h0, l0, h1, l1;
                        split_bf16(p0, h0, l0);
                        split_bf16(p1, h1, l1);
                        *(unsigned int*)((char*)Ph + bofs + 4 * k) = (unsigned int)h0 | ((unsigned int)h1 << 16);
                        *(unsigned int*)((char*)Pl + bofs + 4 * k) = (unsigned int)l0 | ((unsigned int)l1 << 16);
                    }
                }
            }
            // ---- O^T += V^T * P^T (split 3-term, transposed accumulator) ----
#pragma unroll
            for (int kf = 0; kf < 2; ++kf) {
                short8 pa_h[2], pa_l[2];
#pragma unroll
                for (int mf = 0; mf < 2; ++mf) {
                    const int slot = ((mf * 2 + kf) * 4 + g) * 16 + c;
                    pa_h[mf] = *(const short8*)((const char*)Ph + slot * 16);
                    pa_l[mf] = *(const short8*)((const char*)Pl + slot * 16);
                }
#pragma unroll
                for (int nf = 0; nf < 4; ++nf) {
                    const int slot = ((nf * 2 + kf) * 4 + g) * 16 + c;
                    short8 vb_h = *(const short8*)((const char*)Vh + slot * 16);
                    short8 vb_l = *(const short8*)((const char*)Vl + slot * 16);
#pragma unroll
                    for (int mf = 0; mf < 2; ++mf) {
                        o[mf][nf] = __builtin_amdgcn_mfma_f32_16x16x32_bf16(vb_h, pa_h[mf], o[mf][nf], 0, 0, 0);
                        o[mf][nf] = __builtin_amdgcn_mfma_f32_16x16x32_bf16(vb_l, pa_h[mf], o[mf][nf], 0, 0, 0);
                        o[mf][nf] = __builtin_amdgcn_mfma_f32_16x16x32_bf16(vb_h, pa_l[mf], o[mf][nf], 0, 0, 0);
                    }
                }
            }
        }
    }

    // ---- finalize: l reduction, normalize, float4 store ----
    float linv[2];
#pragma unroll
    for (int nf = 0; nf < 2; ++nf) {
        float lt = l_run[nf];
        lt += __shfl_xor(lt, 16);
        lt += __shfl_xor(lt, 32);
        linv[nf] = 1.0f / lt;
    }
#pragma unroll
    for (int mf = 0; mf < 2; ++mf) {
        const float li = linv[mf];
        const int row = qw + 16 * mf + c;
        float* yp = y + ((size_t)b * SEQ + row) * DIM + h * HDIM + 4 * g;
#pragma unroll
        for (int nf = 0; nf < 4; ++nf) {
            float4 ov;
            ov.x = o[mf][nf][0] * li;
            ov.y = o[mf][nf][1] * li;
            ov.z = o[mf][nf][2] * li;
            ov.w = o[mf][nf][3] * li;
            *(float4*)(yp + 16 * nf) = ov;
        }
    }
}

// ---------------------------------------------------------------------------
// Launch
// ---------------------------------------------------------------------------
extern "C" void kernel_launch(void* const* d_in, const int* in_sizes, int n_in,
                              void* d_out, int out_size, void* d_ws, size_t ws_size,
                              hipStream_t stream)
{
    const float* x      = (const float*)d_in[0];
    const float* W_qkv  = (const float*)d_in[1];
    const float* b_qkv  = (const float*)d_in[2];
    const float* W_proj = (const float*)d_in[3];
    const float* b_proj = (const float*)d_in[4];
    float* out = (float*)d_out;

    char* ws = (char*)d_ws;
    float* qkv          = (float*)(ws);                        // 48 MB
    float* y            = (float*)(ws + 50331648);             // 16 MB
    unsigned short* Xh  = (unsigned short*)(ws + 67108864);    // 8 MB (reused for y-frags)
    unsigned short* Xl  = (unsigned short*)(ws + 75497472);    // 8 MB
    unsigned short* Wqh = (unsigned short*)(ws + 83886080);    // 6 MB
    unsigned short* Wql = (unsigned short*)(ws + 90177536);    // 6 MB
    unsigned short* Wph = (unsigned short*)(ws + 96468992);    // 2 MB
    unsigned short* Wpl = (unsigned short*)(ws + 98566144);    // 2 MB

    const int M = BATCH * SEQ;   // 4096

    // 0) weight + activation prep (split to bf16 hi/lo, frag-major units)
    prep_w_kernel<<<3 * DIM / 16, 256, 0, stream>>>(W_qkv, Wqh, Wql, DIM, 3 * DIM);
    prep_w_kernel<<<DIM / 16, 256, 0, stream>>>(W_proj, Wph, Wpl, DIM, DIM);
    prep_a_kernel<<<M / 16, 256, 0, stream>>>(x, Xh, Xl, DIM);

    // 1) QKV projection
    gemm_frag<<<dim3(3 * DIM / 128, M / 128), 256, 0, stream>>>(
        Xh, Xl, Wqh, Wql, b_qkv, qkv, M, 3 * DIM, DIM);

    // 2) causal attention
    attn_mfma_kernel<<<dim3(SEQ / 128, HEADS, BATCH), 256, 0, stream>>>(qkv, y);

    // 3) output projection (y-frags reuse X buffers)
    prep_a_kernel<<<M / 16, 256, 0, stream>>>(y, Xh, Xl, DIM);
    gemm_frag<<<dim3(DIM / 128, M / 128), 256, 0, stream>>>(
        Xh, Xl, Wph, Wpl, b_proj, out, M, DIM, DIM);
}

// Round 10
// 329.257 us; speedup vs baseline: 4.4497x; 1.0592x over previous
//
#include <hip/hip_runtime.h>
#include <math.h>

#define DIM 1024
#define HEADS 16
#define HDIM 64
#define SEQ 2048
#define BATCH 2

typedef __attribute__((ext_vector_type(8))) short short8;
typedef __attribute__((ext_vector_type(4))) float f32x4;

// ---------------------------------------------------------------------------
// bf16 split helpers (round-to-nearest-even)
// ---------------------------------------------------------------------------
__device__ __forceinline__ unsigned short bf16_rtn(float x) {
    union { float f; unsigned int u; } c; c.f = x;
    unsigned int r = c.u + 0x7fffu + ((c.u >> 16) & 1u);
    return (unsigned short)(r >> 16);
}
__device__ __forceinline__ float bf16_to_f(unsigned short h) {
    union { unsigned int u; float f; } c; c.u = ((unsigned int)h) << 16;
    return c.f;
}
__device__ __forceinline__ void split_bf16(float x, unsigned short& hi, unsigned short& lo) {
    hi = bf16_rtn(x);
    lo = bf16_rtn(x - bf16_to_f(hi));
}

// ---------------------------------------------------------------------------
// prep_a: A f32 [M][K] -> Ah/Al bf16 frag-major units.
// Unit (mu,ku) = 1KB: [g=4][c=16][e=8]; element = A[mu*16+c][ku*32+g*8+e].
// ---------------------------------------------------------------------------
__global__ __launch_bounds__(256) void prep_a_kernel(
    const float* __restrict__ A, unsigned short* __restrict__ Ah,
    unsigned short* __restrict__ Al, int K)
{
    const int mu = blockIdx.x;
    const int nku = K >> 5;
    const int t = threadIdx.x;
    const int c = t & 15;
    const int pb = t >> 4;
    const int npairs = K >> 3;
    for (int p = pb; p < npairs; p += 16) {
        const int ku = p >> 2, g = p & 3;
        const float* src = A + (size_t)(mu * 16 + c) * K + ku * 32 + g * 8;
        const float4 f0 = ((const float4*)src)[0];
        const float4 f1 = ((const float4*)src)[1];
        const float tf[8] = {f0.x, f0.y, f0.z, f0.w, f1.x, f1.y, f1.z, f1.w};
        unsigned int hw[4], lw[4];
#pragma unroll
        for (int j = 0; j < 4; ++j) {
            unsigned short h0, l0, h1, l1;
            split_bf16(tf[2 * j], h0, l0);
            split_bf16(tf[2 * j + 1], h1, l1);
            hw[j] = (unsigned int)h0 | ((unsigned int)h1 << 16);
            lw[j] = (unsigned int)l0 | ((unsigned int)l1 << 16);
        }
        const size_t off = ((size_t)mu * nku + ku) * 512 + g * 128 + c * 8;
        *(uint4*)(Ah + off) = *(uint4*)hw;
        *(uint4*)(Al + off) = *(uint4*)lw;
    }
}

// ---------------------------------------------------------------------------
// prep_w: W f32 [K][N] -> Wh/Wl frag-major units over (nu,ku) (transposed).
// ---------------------------------------------------------------------------
__global__ __launch_bounds__(256) void prep_w_kernel(
    const float* __restrict__ W, unsigned short* __restrict__ Wh,
    unsigned short* __restrict__ Wl, int K, int N)
{
    const int nu = blockIdx.x;
    const int nku = K >> 5;
    const int t = threadIdx.x;
    const int c = t & 15;
    const int pb = t >> 4;
    const int npairs = K >> 3;
    for (int p = pb; p < npairs; p += 16) {
        const int ku = p >> 2, g = p & 3;
        unsigned int hw[4], lw[4];
#pragma unroll
        for (int j = 0; j < 4; ++j) {
            const float v0 = W[(size_t)(ku * 32 + g * 8 + 2 * j) * N + nu * 16 + c];
            const float v1 = W[(size_t)(ku * 32 + g * 8 + 2 * j + 1) * N + nu * 16 + c];
            unsigned short h0, l0, h1, l1;
            split_bf16(v0, h0, l0);
            split_bf16(v1, h1, l1);
            hw[j] = (unsigned int)h0 | ((unsigned int)h1 << 16);
            lw[j] = (unsigned int)l0 | ((unsigned int)l1 << 16);
        }
        const size_t off = ((size_t)nu * nku + ku) * 512 + g * 128 + c * 8;
        *(uint4*)(Wh + off) = *(uint4*)hw;
        *(uint4*)(Wl + off) = *(uint4*)lw;
    }
}

// ---------------------------------------------------------------------------
// prep_kv: split K and (transposed) V from KVbuf f32 [B*T][2048] into
// frag-major hi/lo chunk blocks (8KB per buffer per chunk of 64 keys).
// ---------------------------------------------------------------------------
__global__ __launch_bounds__(256) void prep_kv_kernel(
    const float* __restrict__ KV,
    unsigned short* __restrict__ Kfh, unsigned short* __restrict__ Kfl,
    unsigned short* __restrict__ Vfh, unsigned short* __restrict__ Vfl)
{
    const int ch = blockIdx.x, h = blockIdx.y, b = blockIdx.z;
    const int kb = ch * 64;
    const int t = threadIdx.x;
    const size_t obase = ((size_t)((b * HEADS + h) * 32 + ch)) * 4096;
    const float* base = KV + (size_t)b * SEQ * 2048;

    // K part
#pragma unroll
    for (int i = 0; i < 2; ++i) {
        const int s = t + 256 * i;
        const int sc = s & 15, sg = (s >> 4) & 3, skf = (s >> 6) & 1, smf = s >> 7;
        const int row = kb + 16 * smf + sc;
        const int d0 = 32 * skf + 8 * sg;
        const float4* kp = (const float4*)(base + (size_t)row * 2048 + h * HDIM + d0);
        const float4 f0 = kp[0], f1 = kp[1];
        const float tf[8] = {f0.x, f0.y, f0.z, f0.w, f1.x, f1.y, f1.z, f1.w};
        unsigned int hw[4], lw[4];
#pragma unroll
        for (int j = 0; j < 4; ++j) {
            unsigned short h0, l0, h1, l1;
            split_bf16(tf[2 * j], h0, l0);
            split_bf16(tf[2 * j + 1], h1, l1);
            hw[j] = (unsigned int)h0 | ((unsigned int)h1 << 16);
            lw[j] = (unsigned int)l0 | ((unsigned int)l1 << 16);
        }
        *(uint4*)(Kfh + obase + s * 8) = *(uint4*)hw;
        *(uint4*)(Kfl + obase + s * 8) = *(uint4*)lw;
    }
    // V part (transpose gather)
#pragma unroll
    for (int i = 0; i < 2; ++i) {
        const int s = t + 256 * i;
        const int c = s & 15, g = (s >> 4) & 3, kf = (s >> 6) & 1, nf = s >> 7;
        const int dim = 16 * nf + c;
        const float* vp = base + (size_t)(kb + 32 * kf + 8 * g) * 2048 + 1024 + h * HDIM + dim;
        float tf[8];
#pragma unroll
        for (int e = 0; e < 8; ++e) tf[e] = vp[(size_t)e * 2048];
        unsigned int hw[4], lw[4];
#pragma unroll
        for (int j = 0; j < 4; ++j) {
            unsigned short h0, l0, h1, l1;
            split_bf16(tf[2 * j], h0, l0);
            split_bf16(tf[2 * j + 1], h1, l1);
            hw[j] = (unsigned int)h0 | ((unsigned int)h1 << 16);
            lw[j] = (unsigned int)l0 | ((unsigned int)l1 << 16);
        }
        *(uint4*)(Vfh + obase + s * 8) = *(uint4*)hw;
        *(uint4*)(Vfl + obase + s * 8) = *(uint4*)lw;
    }
}

// ---------------------------------------------------------------------------
// Split-bf16 MFMA GEMM on frag-major inputs, split C output:
// cols < qsplit -> Cq (ld ldq), cols >= qsplit -> Ckv (ld ldkv, col - qsplit).
// ---------------------------------------------------------------------------
__global__ __launch_bounds__(256) void gemm_frag(
    const unsigned short* __restrict__ Ah, const unsigned short* __restrict__ Al,
    const unsigned short* __restrict__ Bh, const unsigned short* __restrict__ Bl,
    const float* __restrict__ bias,
    float* __restrict__ Cq, int ldq,
    float* __restrict__ Ckv, int ldkv, int qsplit,
    int M, int N, int K)
{
    __shared__ __align__(16) unsigned short sm[16384];
    const int nku = K >> 5;
    const int tid = threadIdx.x;
    const int w = tid >> 6, lane = tid & 63;
    const int c = lane & 15, g = lane >> 4;
    const int bm = blockIdx.y * 128, bn = blockIdx.x * 128;
    const int wm = (w >> 1) * 64, wn = (w & 1) * 64;

    const unsigned short* srcp[8];
    int dsto[8];
#pragma unroll
    for (int i = 0; i < 8; ++i) {
        const int flat = i * 256 + tid;
        const int luid = flat >> 6, gran = flat & 63;
        const int buf = luid >> 3, uloc = luid & 7;
        const unsigned short* base = (buf == 0) ? Ah : (buf == 1) ? Al : (buf == 2) ? Bh : Bl;
        const int rb = (buf < 2) ? bm : bn;
        srcp[i] = base + ((size_t)(rb / 16 + uloc) * nku) * 512 + gran * 8;
        dsto[i] = flat * 8;
    }

    f32x4 acc[4][4];
#pragma unroll
    for (int i = 0; i < 4; ++i)
#pragma unroll
        for (int j = 0; j < 4; ++j) acc[i][j] = (f32x4){0.f, 0.f, 0.f, 0.f};

    short8 nxt[8];
#pragma unroll
    for (int i = 0; i < 8; ++i) nxt[i] = *(const short8*)(srcp[i]);

    for (int ks = 0; ks < nku; ++ks) {
        __syncthreads();
#pragma unroll
        for (int i = 0; i < 8; ++i) *(short8*)(sm + dsto[i]) = nxt[i];
        __syncthreads();

        if (ks + 1 < nku) {
            const int off = (ks + 1) * 512;
#pragma unroll
            for (int i = 0; i < 8; ++i) nxt[i] = *(const short8*)(srcp[i] + off);
        }

        short8 ahf[4], alf[4], bhf[4], blf[4];
        const int lo = lane * 8;
#pragma unroll
        for (int f = 0; f < 4; ++f) {
            ahf[f] = *(const short8*)(sm + (wm / 16 + f) * 512 + lo);
            alf[f] = *(const short8*)(sm + (8 + wm / 16 + f) * 512 + lo);
            bhf[f] = *(const short8*)(sm + (16 + wn / 16 + f) * 512 + lo);
            blf[f] = *(const short8*)(sm + (24 + wn / 16 + f) * 512 + lo);
        }
#pragma unroll
        for (int fm = 0; fm < 4; ++fm)
#pragma unroll
            for (int fn = 0; fn < 4; ++fn) {
                f32x4 cc = acc[fm][fn];
                cc = __builtin_amdgcn_mfma_f32_16x16x32_bf16(bhf[fn], ahf[fm], cc, 0, 0, 0);
                cc = __builtin_amdgcn_mfma_f32_16x16x32_bf16(blf[fn], ahf[fm], cc, 0, 0, 0);
                cc = __builtin_amdgcn_mfma_f32_16x16x32_bf16(bhf[fn], alf[fm], cc, 0, 0, 0);
                acc[fm][fn] = cc;
            }
    }

    // epilogue: acc[fm][fn][r] = C[bm+wm+fm*16+c][bn+wn+fn*16+4g+r]
    const int gc0 = bn + wn;
    float* cbase; int ldc, ccol;
    if (gc0 < qsplit) { cbase = Cq; ldc = ldq; ccol = gc0; }
    else { cbase = Ckv; ldc = ldkv; ccol = gc0 - qsplit; }

    float4 bv[4];
#pragma unroll
    for (int fn = 0; fn < 4; ++fn)
        bv[fn] = *(const float4*)&bias[gc0 + fn * 16 + 4 * g];
#pragma unroll
    for (int fm = 0; fm < 4; ++fm) {
        const int row = bm + wm + fm * 16 + c;
        float* cp = cbase + (size_t)row * ldc + ccol + 4 * g;
#pragma unroll
        for (int fn = 0; fn < 4; ++fn) {
            float4 o;
            o.x = acc[fm][fn][0] + bv[fn].x;
            o.y = acc[fm][fn][1] + bv[fn].y;
            o.z = acc[fm][fn][2] + bv[fn].z;
            o.w = acc[fm][fn][3] + bv[fn].w;
            *(float4*)(cp + fn * 16) = o;
        }
    }
}

// ---------------------------------------------------------------------------
// MFMA flash attention (causal): pre-split K/V frag copies with next-chunk
// prefetch, exp2 softmax, split-frag Y output (Yfh/Yfl, prep_a layout).
// ---------------------------------------------------------------------------
__global__ __launch_bounds__(256) void attn_mfma_kernel(
    const float* __restrict__ Q,
    const unsigned short* __restrict__ Kfh, const unsigned short* __restrict__ Kfl,
    const unsigned short* __restrict__ Vfh, const unsigned short* __restrict__ Vfl,
    unsigned short* __restrict__ Yfh, unsigned short* __restrict__ Yfl)
{
    __shared__ __align__(16) char smem[49152];
    unsigned short* Kh = (unsigned short*)smem;              // 8K (later P of wave 0)
    unsigned short* Kl = (unsigned short*)(smem + 8192);     // 8K (later P of wave 1)
    unsigned short* Vh = (unsigned short*)(smem + 16384);    // 8K
    unsigned short* Vl = (unsigned short*)(smem + 24576);    // 8K

    const int tid = threadIdx.x;
    const int w = tid >> 6, lane = tid & 63;
    const int c = lane & 15;
    const int g = lane >> 4;

    const int tilemax = (int)gridDim.x - 1;
    const int tile = blockIdx.z ? (int)blockIdx.x : (tilemax - (int)blockIdx.x);
    const int qb = tile * 128;
    const int h = blockIdx.y, b = blockIdx.z;
    const int qw = qb + 32 * w;

    char* Pw = (w < 2) ? (smem + 8192 * w) : (smem + 32768 + 8192 * (w - 2));
    unsigned short* Ph = (unsigned short*)Pw;
    unsigned short* Pl = (unsigned short*)(Pw + 4096);

    const float QS = 0.125f * 1.44269504088896341f;   // (1/sqrt(64)) * log2(e)

    // ---- Q fragments (scaled, split hi/lo) ----
    short8 q_hi[2][2], q_lo[2][2];
#pragma unroll
    for (int nf = 0; nf < 2; ++nf)
#pragma unroll
        for (int kf = 0; kf < 2; ++kf) {
            const int row = qw + 16 * nf + c;
            const int d0 = 32 * kf + 8 * g;
            const float4* qp = (const float4*)(Q + ((size_t)b * SEQ + row) * DIM + h * HDIM + d0);
            float4 f0 = qp[0], f1 = qp[1];
            float tf[8] = {f0.x, f0.y, f0.z, f0.w, f1.x, f1.y, f1.z, f1.w};
#pragma unroll
            for (int j = 0; j < 8; ++j) {
                unsigned short hh, ll;
                split_bf16(tf[j] * QS, hh, ll);
                q_hi[nf][kf][j] = (short)hh;
                q_lo[nf][kf][j] = (short)ll;
            }
        }

    f32x4 o[2][4];
#pragma unroll
    for (int i = 0; i < 2; ++i)
#pragma unroll
        for (int j = 0; j < 4; ++j) o[i][j] = (f32x4){0.f, 0.f, 0.f, 0.f};
    float m_run[2] = {-3.0e30f, -3.0e30f};
    float l_run[2] = {0.f, 0.f};

    const size_t fbase = ((size_t)(b * HEADS + h)) * (32 * 4096);
    const int nch = qb / 64 + 2;

    // prefetch chunk 0 (8 x b128 per thread)
    short8 nxt[8];
    {
        const size_t cb = fbase;
        nxt[0] = *(const short8*)(Kfh + cb + (size_t)tid * 8);
        nxt[1] = *(const short8*)(Kfh + cb + (size_t)(tid + 256) * 8);
        nxt[2] = *(const short8*)(Kfl + cb + (size_t)tid * 8);
        nxt[3] = *(const short8*)(Kfl + cb + (size_t)(tid + 256) * 8);
        nxt[4] = *(const short8*)(Vfh + cb + (size_t)tid * 8);
        nxt[5] = *(const short8*)(Vfh + cb + (size_t)(tid + 256) * 8);
        nxt[6] = *(const short8*)(Vfl + cb + (size_t)tid * 8);
        nxt[7] = *(const short8*)(Vfl + cb + (size_t)(tid + 256) * 8);
    }

    for (int ch = 0; ch < nch; ++ch) {
        const int kb = ch * 64;
        __syncthreads();   // B1: prior chunk's LDS reads (incl. P region) done

        *(short8*)((char*)Kh + tid * 16) = nxt[0];
        *(short8*)((char*)Kh + (tid + 256) * 16) = nxt[1];
        *(short8*)((char*)Kl + tid * 16) = nxt[2];
        *(short8*)((char*)Kl + (tid + 256) * 16) = nxt[3];
        *(short8*)((char*)Vh + tid * 16) = nxt[4];
        *(short8*)((char*)Vh + (tid + 256) * 16) = nxt[5];
        *(short8*)((char*)Vl + tid * 16) = nxt[6];
        *(short8*)((char*)Vl + (tid + 256) * 16) = nxt[7];
        __syncthreads();   // B2: staging visible

        if (ch + 1 < nch) {   // prefetch next chunk (overlaps MFMA below)
            const size_t cb = fbase + (size_t)(ch + 1) * 4096;
            nxt[0] = *(const short8*)(Kfh + cb + (size_t)tid * 8);
            nxt[1] = *(const short8*)(Kfh + cb + (size_t)(tid + 256) * 8);
            nxt[2] = *(const short8*)(Kfl + cb + (size_t)tid * 8);
            nxt[3] = *(const short8*)(Kfl + cb + (size_t)(tid + 256) * 8);
            nxt[4] = *(const short8*)(Vfh + cb + (size_t)tid * 8);
            nxt[5] = *(const short8*)(Vfh + cb + (size_t)(tid + 256) * 8);
            nxt[6] = *(const short8*)(Vfl + cb + (size_t)tid * 8);
            nxt[7] = *(const short8*)(Vfl + cb + (size_t)(tid + 256) * 8);
        }

        const bool active = (kb <= qw + 31);
        const bool diag = active && (kb + 63 > qw);
        f32x4 st[4][2];
        float fscale[2];

        if (active) {
            // ---- S^T = K * Q^T (split 3-term; S in log2-e units) ----
#pragma unroll
            for (int mf = 0; mf < 4; ++mf)
#pragma unroll
                for (int nf = 0; nf < 2; ++nf) st[mf][nf] = (f32x4){0.f, 0.f, 0.f, 0.f};
#pragma unroll
            for (int kf = 0; kf < 2; ++kf)
#pragma unroll
                for (int mf = 0; mf < 4; ++mf) {
                    const int slot = ((mf * 2 + kf) * 4 + g) * 16 + c;
                    short8 ah = *(const short8*)((const char*)Kh + slot * 16);
                    short8 al = *(const short8*)((const char*)Kl + slot * 16);
#pragma unroll
                    for (int nf = 0; nf < 2; ++nf) {
                        st[mf][nf] = __builtin_amdgcn_mfma_f32_16x16x32_bf16(ah, q_hi[nf][kf], st[mf][nf], 0, 0, 0);
                        st[mf][nf] = __builtin_amdgcn_mfma_f32_16x16x32_bf16(ah, q_lo[nf][kf], st[mf][nf], 0, 0, 0);
                        st[mf][nf] = __builtin_amdgcn_mfma_f32_16x16x32_bf16(al, q_hi[nf][kf], st[mf][nf], 0, 0, 0);
                    }
                }
            // ---- mask + online softmax state (base-2) ----
#pragma unroll
            for (int nf = 0; nf < 2; ++nf) {
                float cm = -3.0e30f;
#pragma unroll
                for (int mf = 0; mf < 4; ++mf)
#pragma unroll
                    for (int r = 0; r < 4; ++r) {
                        float s = st[mf][nf][r];
                        if (diag && (kb + 16 * mf + 4 * g + r > qw + 16 * nf + c)) s = -3.0e30f;
                        st[mf][nf][r] = s;
                        cm = fmaxf(cm, s);
                    }
                cm = fmaxf(cm, __shfl_xor(cm, 16));
                cm = fmaxf(cm, __shfl_xor(cm, 32));
                const float mnew = fmaxf(m_run[nf], cm);
                fscale[nf] = exp2f(m_run[nf] - mnew);
                m_run[nf] = mnew;
                l_run[nf] *= fscale[nf];
            }
            // ---- O rescale ----
#pragma unroll
            for (int mf = 0; mf < 2; ++mf) {
                const float fo = fscale[mf];
#pragma unroll
                for (int nf = 0; nf < 4; ++nf) {
                    o[mf][nf][0] *= fo; o[mf][nf][1] *= fo;
                    o[mf][nf][2] *= fo; o[mf][nf][3] *= fo;
                }
            }
        }
        __syncthreads();   // B3: K reads done; P may overwrite K space

        if (active) {
            // ---- P = exp2(S - m), split hi/lo, frag-major P slots ----
#pragma unroll
            for (int nf = 0; nf < 2; ++nf) {
#pragma unroll
                for (int mf = 0; mf < 4; ++mf) {
                    const int slot = ((nf * 2 + (mf >> 1)) * 4 + ((2 * mf + (g >> 1)) & 3)) * 16 + c;
                    const int bofs = slot * 16 + 8 * (g & 1);
#pragma unroll
                    for (int k = 0; k < 2; ++k) {
                        const float p0 = exp2f(st[mf][nf][2 * k] - m_run[nf]);
                        const float p1 = exp2f(st[mf][nf][2 * k + 1] - m_run[nf]);
                        l_run[nf] += p0 + p1;
                        unsigned short h0, l0, h1, l1;
                        split_bf16(p0, h0, l0);
                        split_bf16(p1, h1, l1);
                        *(unsigned int*)((char*)Ph + bofs + 4 * k) = (unsigned int)h0 | ((unsigned int)h1 << 16);
                        *(unsigned int*)((char*)Pl + bofs + 4 * k) = (unsigned int)l0 | ((unsigned int)l1 << 16);
                    }
                }
            }
            // ---- O^T += V^T * P^T (split 3-term, transposed accumulator) ----
#pragma unroll
            for (int kf = 0; kf < 2; ++kf) {
                short8 pa_h[2], pa_l[2];
#pragma unroll
                for (int mf = 0; mf < 2; ++mf) {
                    const int slot = ((mf * 2 + kf) * 4 + g) * 16 + c;
                    pa_h[mf] = *(const short8*)((const char*)Ph + slot * 16);
                    pa_l[mf] = *(const short8*)((const char*)Pl + slot * 16);
                }
#pragma unroll
                for (int nf = 0; nf < 4; ++nf) {
                    const int slot = ((nf * 2 + kf) * 4 + g) * 16 + c;
                    short8 vb_h = *(const short8*)((const char*)Vh + slot * 16);
                    short8 vb_l = *(const short8*)((const char*)Vl + slot * 16);
#pragma unroll
                    for (int mf = 0; mf < 2; ++mf) {
                        o[mf][nf] = __builtin_amdgcn_mfma_f32_16x16x32_bf16(vb_h, pa_h[mf], o[mf][nf], 0, 0, 0);
                        o[mf][nf] = __builtin_amdgcn_mfma_f32_16x16x32_bf16(vb_l, pa_h[mf], o[mf][nf], 0, 0, 0);
                        o[mf][nf] = __builtin_amdgcn_mfma_f32_16x16x32_bf16(vb_h, pa_l[mf], o[mf][nf], 0, 0, 0);
                    }
                }
            }
        }
    }

    // ---- finalize: l reduction, normalize, write split Y-frags ----
    float linv[2];
#pragma unroll
    for (int nf = 0; nf < 2; ++nf) {
        float lt = l_run[nf];
        lt += __shfl_xor(lt, 16);
        lt += __shfl_xor(lt, 32);
        linv[nf] = 1.0f / lt;
    }
#pragma unroll
    for (int mf = 0; mf < 2; ++mf) {
        const float li = linv[mf];
        // FIX (round 9): mu must be the GLOBAL M-row /16 — include batch offset.
        const int mu = (b * SEQ + qw + 16 * mf) >> 4;
#pragma unroll
        for (int nf = 0; nf < 4; ++nf) {
            const int D0 = h * HDIM + 16 * nf + 4 * g;
            const int ku = D0 >> 5;
            const int gp = (D0 >> 3) & 3;
            const int e0 = D0 & 7;             // 4*(g&1)
            const size_t off = ((size_t)mu * 32 + ku) * 512 + (gp * 16 + c) * 8 + e0;
            unsigned short h0, l0, h1, l1, h2, l2, h3, l3;
            split_bf16(o[mf][nf][0] * li, h0, l0);
            split_bf16(o[mf][nf][1] * li, h1, l1);
            split_bf16(o[mf][nf][2] * li, h2, l2);
            split_bf16(o[mf][nf][3] * li, h3, l3);
            uint2 hy, ly;
            hy.x = (unsigned int)h0 | ((unsigned int)h1 << 16);
            hy.y = (unsigned int)h2 | ((unsigned int)h3 << 16);
            ly.x = (unsigned int)l0 | ((unsigned int)l1 << 16);
            ly.y = (unsigned int)l2 | ((unsigned int)l3 << 16);
            *(uint2*)(Yfh + off) = hy;
            *(uint2*)(Yfl + off) = ly;
        }
    }
}

// ---------------------------------------------------------------------------
// Launch.  ws map (peak 88 MB, all phases hazard-checked):
//   [0,16M)    Qbuf f32           (gemmQKV -> attn)
//   [16M,48M)  KVbuf f32          (gemmQKV -> prep_kv); then Yfh/Yfl (attn -> proj)
//   [48M,80M)  Wq frags + X frags (prep -> gemmQKV); then Kfh/Kfl/Vfh/Vfl
//   [80M,84M)  Wp frags           (prep -> gemmProj)
// ---------------------------------------------------------------------------
extern "C" void kernel_launch(void* const* d_in, const int* in_sizes, int n_in,
                              void* d_out, int out_size, void* d_ws, size_t ws_size,
                              hipStream_t stream)
{
    const float* x      = (const float*)d_in[0];
    const float* W_qkv  = (const float*)d_in[1];
    const float* b_qkv  = (const float*)d_in[2];
    const float* W_proj = (const float*)d_in[3];
    const float* b_proj = (const float*)d_in[4];
    float* out = (float*)d_out;

    char* ws = (char*)d_ws;
    float* Qbuf  = (float*)(ws);                               // 16 MB
    float* KVbuf = (float*)(ws + 16777216);                    // 32 MB
    unsigned short* Yfh = (unsigned short*)(ws + 16777216);    // 8 MB (over dead KVbuf)
    unsigned short* Yfl = (unsigned short*)(ws + 25165824);    // 8 MB
    unsigned short* Wqh = (unsigned short*)(ws + 50331648);    // 6 MB
    unsigned short* Wql = (unsigned short*)(ws + 56623104);    // 6 MB
    unsigned short* Xh  = (unsigned short*)(ws + 62914560);    // 8 MB
    unsigned short* Xl  = (unsigned short*)(ws + 71303168);    // 8 MB (ends 79691776)
    unsigned short* Kfh = (unsigned short*)(ws + 50331648);    // 8 MB (over dead Wq/X)
    unsigned short* Kfl = (unsigned short*)(ws + 58720256);    // 8 MB
    unsigned short* Vfh = (unsigned short*)(ws + 67108864);    // 8 MB
    unsigned short* Vfl = (unsigned short*)(ws + 75497472);    // 8 MB (ends 83886080)
    unsigned short* Wph = (unsigned short*)(ws + 83886080);    // 2 MB
    unsigned short* Wpl = (unsigned short*)(ws + 85983232);    // 2 MB (ends 88080384)

    const int M = BATCH * SEQ;   // 4096

    // 0) weight + activation prep
    prep_w_kernel<<<3 * DIM / 16, 256, 0, stream>>>(W_qkv, Wqh, Wql, DIM, 3 * DIM);
    prep_w_kernel<<<DIM / 16, 256, 0, stream>>>(W_proj, Wph, Wpl, DIM, DIM);
    prep_a_kernel<<<M / 16, 256, 0, stream>>>(x, Xh, Xl, DIM);

    // 1) QKV projection -> Qbuf (cols 0..1023) + KVbuf (cols 1024..3071)
    gemm_frag<<<dim3(3 * DIM / 128, M / 128), 256, 0, stream>>>(
        Xh, Xl, Wqh, Wql, b_qkv, Qbuf, DIM, KVbuf, 2048, 1024, M, 3 * DIM, DIM);

    // 2) K/V frag prep (split + V transpose), then causal attention -> Y frags
    prep_kv_kernel<<<dim3(SEQ / 64, HEADS, BATCH), 256, 0, stream>>>(
        KVbuf, Kfh, Kfl, Vfh, Vfl);
    attn_mfma_kernel<<<dim3(SEQ / 128, HEADS, BATCH), 256, 0, stream>>>(
        Qbuf, Kfh, Kfl, Vfh, Vfl, Yfh, Yfl);

    // 3) output projection (reads Y frags directly)
    gemm_frag<<<dim3(DIM / 128, M / 128), 256, 0, stream>>>(
        Yfh, Yfl, Wph, Wpl, b_proj, out, DIM, out, DIM, DIM, M, DIM, DIM);
}